// Round 8
// baseline (879.178 us; speedup 1.0000x reference)
//
#include <hip/hip_runtime.h>
#include <hip/hip_bf16.h>
#include <math.h>

// Shapes (fixed): B=32, C=3, H=128, W=128, HID=64, NP=64, P=16, E=768, NH=4, dh=192
// Output = concat(patches (32*64*3*16*16), translate (32*64*2)), fp32.

#define PI_F 3.14159265358979323846f

typedef float f32x4 __attribute__((ext_vector_type(4)));
typedef short short8 __attribute__((ext_vector_type(8)));
typedef unsigned short us4 __attribute__((ext_vector_type(4)));
typedef __hip_bfloat16 bf16;

__device__ __forceinline__ void async16(const void* g, void* l) {
  __builtin_amdgcn_global_load_lds(
      (const __attribute__((address_space(1))) void*)g,
      (__attribute__((address_space(3))) void*)l, 16, 0, 0);
}

__device__ __forceinline__ short8 f8_to_bf8(float4 a, float4 b) {
  bf16 v[8] = {__float2bfloat16(a.x), __float2bfloat16(a.y),
               __float2bfloat16(a.z), __float2bfloat16(a.w),
               __float2bfloat16(b.x), __float2bfloat16(b.y),
               __float2bfloat16(b.z), __float2bfloat16(b.w)};
  return *(const short8*)v;
}

// ---------------- bf16 MFMA NT GEMM, fp32 B weights converted in staging ----------------
// C[M,N] = A_bf16[M,K] * Bw_f32[N,K]^T. 128x128 tile, BK=32, 4 waves (2x2 of 64x64).
// 1-D grid of (M/128)*(N/128)*S blocks, z = id % S (XCD-affine split-K), tile = id / S
// with GROUP_M=8 supertile swizzle.
// MODE 0: fp32 partial to Cout + z*M*N (no bias); MODE 2: bf16 + bias.
template <int MODE, int S>
__global__ __launch_bounds__(256) void gemm_bf16(
    const unsigned short* __restrict__ A, const float* __restrict__ Bw,
    const float* __restrict__ bias, void* __restrict__ Cout,
    int M, int N, int K, int kchunk) {
  __shared__ unsigned short As[128 * 32];
  __shared__ unsigned short Bs[128 * 32];
  const int tid = threadIdx.x;
  const int idz = (S > 1) ? (blockIdx.x % S) : 0;
  int l = (S > 1) ? (blockIdx.x / S) : blockIdx.x;
  const int bmT = M >> 7, bnT = N >> 7;
  const int gsize = 8 * bnT;
  int gid = l / gsize;
  int rem = l - gid * gsize;
  int fm = gid * 8;
  int gsz = bmT - fm; if (gsz > 8) gsz = 8;
  const int bm = (fm + rem % gsz) << 7;
  const int bn = (rem / gsz) << 7;
  const int k0 = idz * kchunk;
  const int wave = tid >> 6;
  const int lane = tid & 63;
  const int wm = (wave & 1) << 6, wn = (wave >> 1) << 6;
  const int r0 = tid >> 2;
  const int c0 = (tid & 3) << 3;
  const unsigned short* Ag0 = A + (size_t)(bm + r0) * K + k0 + c0;
  const unsigned short* Ag1 = Ag0 + (size_t)64 * K;
  const float* Bf0 = Bw + (size_t)(bn + r0) * K + k0 + c0;
  const float* Bf1 = Bf0 + (size_t)64 * K;
  unsigned short* Al = As + wave * 512;
  f32x4 acc[4][4] = {};
  const int fr = lane & 15;
  const int fk = (lane >> 4) << 3;
  for (int kt = 0; kt < kchunk; kt += 32) {
    float4 b0a = *(const float4*)(Bf0 + kt);
    float4 b0b = *(const float4*)(Bf0 + kt + 4);
    float4 b1a = *(const float4*)(Bf1 + kt);
    float4 b1b = *(const float4*)(Bf1 + kt + 4);
    async16(Ag0 + kt, Al);
    async16(Ag1 + kt, Al + 2048);
    *(short8*)(Bs + (tid << 3)) = f8_to_bf8(b0a, b0b);
    *(short8*)(Bs + (tid << 3) + 2048) = f8_to_bf8(b1a, b1b);
    __syncthreads();
    short8 af[4], bf[4];
    #pragma unroll
    for (int i = 0; i < 4; ++i)
      af[i] = *(const short8*)(As + ((wm + i * 16 + fr) << 5) + fk);
    #pragma unroll
    for (int i = 0; i < 4; ++i)
      bf[i] = *(const short8*)(Bs + ((wn + i * 16 + fr) << 5) + fk);
    #pragma unroll
    for (int mi = 0; mi < 4; ++mi)
      #pragma unroll
      for (int ni = 0; ni < 4; ++ni)
        acc[mi][ni] = __builtin_amdgcn_mfma_f32_16x16x32_bf16(af[mi], bf[ni], acc[mi][ni], 0, 0, 0);
    __syncthreads();
  }
  const int cr = (lane >> 4) << 2;
  const int cc = lane & 15;
  if (MODE == 0) {
    float* C = (float*)Cout + (size_t)idz * M * N;
    #pragma unroll
    for (int mi = 0; mi < 4; ++mi)
      #pragma unroll
      for (int ni = 0; ni < 4; ++ni) {
        int col = bn + wn + ni * 16 + cc;
        #pragma unroll
        for (int r = 0; r < 4; ++r)
          C[(size_t)(bm + wm + mi * 16 + cr + r) * N + col] = acc[mi][ni][r];
      }
  } else {
    #pragma unroll
    for (int ni = 0; ni < 4; ++ni) {
      int col = bn + wn + ni * 16 + cc;
      float bv = bias[col];
      #pragma unroll
      for (int mi = 0; mi < 4; ++mi)
        #pragma unroll
        for (int r = 0; r < 4; ++r) {
          size_t idx = (size_t)(bm + wm + mi * 16 + cr + r) * N + col;
          ((bf16*)Cout)[idx] = __float2bfloat16(acc[mi][ni][r] + bv);
        }
    }
  }
}

// ---------------- split-K reduce (vectorized x4): out_bf16 = act(sum_z part[z]+bias) -----
__global__ __launch_bounds__(256) void reduce_bias_k(
    const float* __restrict__ part, const float* __restrict__ bias,
    bf16* __restrict__ out, int MN, int N, int S, int relu) {
  int i = blockIdx.x * 256 + threadIdx.x;
  if (i >= (MN >> 2)) return;
  float4 s = ((const float4*)part)[i];
  for (int z = 1; z < S; ++z) {
    float4 q = *(const float4*)(part + (size_t)z * MN + i * 4);
    s.x += q.x; s.y += q.y; s.z += q.z; s.w += q.w;
  }
  int nb = (i * 4) % N;
  float4 bv = *(const float4*)(bias + nb);
  s.x += bv.x; s.y += bv.y; s.z += bv.z; s.w += bv.w;
  if (relu) {
    s.x = fmaxf(s.x, 0.f); s.y = fmaxf(s.y, 0.f);
    s.z = fmaxf(s.z, 0.f); s.w = fmaxf(s.w, 0.f);
  }
  bf16 vals[4] = {__float2bfloat16(s.x), __float2bfloat16(s.y),
                  __float2bfloat16(s.z), __float2bfloat16(s.w)};
  *(us4*)(out + (size_t)i * 4) = *(const us4*)vals;
}

// ---------------- conv2 weight transpose: wcl[tap][oc][ic] bf16 ----------------
__global__ __launch_bounds__(256) void cvt_wcl_k(
    const float* __restrict__ w, bf16* __restrict__ wcl) {
  int i = blockIdx.x * 256 + threadIdx.x;
  if (i >= 36864) return;
  int ic = i & 63, oc = (i >> 6) & 63, s = i >> 12;
  wcl[i] = __float2bfloat16(w[oc * 576 + ic * 9 + s]);
}

// ---------------- conv1 (fast): (32,3,128,128) -> bf16 (32,64,128,128), 3x3 SAME, ReLU ---
__global__ __launch_bounds__(256) void conv3x3_relu_c3_fast(
    const float* __restrict__ x, const float* __restrict__ w,
    const float* __restrict__ bias, bf16* __restrict__ out) {
  __shared__ float xs[3][4][132];
  __shared__ float wsm[3][9][64];
  const int tid = threadIdx.x;
  const int b = blockIdx.y;
  const int y0 = blockIdx.x * 2;
  const int xg = (tid & 15) * 8;
  const int row = (tid >> 4) & 1;
  const int oc0 = (tid >> 5) * 8;
  for (int i = tid; i < 3 * 4 * 132; i += 256) {
    int c = i % 132;
    int r = (i / 132) % 4;
    int ic = i / (132 * 4);
    int gy = y0 + r - 1;
    int gx = c - 1;
    float v = 0.f;
    if ((unsigned)gy < 128u && (unsigned)gx < 128u)
      v = x[((size_t)(b * 3 + ic) << 14) + gy * 128 + gx];
    xs[ic][r][c] = v;
  }
  for (int i = tid; i < 3 * 9 * 64; i += 256) {
    int oc = i & 63;
    int k = (i >> 6) % 9;
    int ic = i / (64 * 9);
    wsm[ic][k][oc] = w[oc * 27 + ic * 9 + k];
  }
  __syncthreads();
  float acc[8][8] = {};
  #pragma unroll
  for (int ic = 0; ic < 3; ++ic) {
    #pragma unroll
    for (int ky = 0; ky < 3; ++ky) {
      const float* rp = &xs[ic][row + ky][xg];
      float4 r0 = *(const float4*)(rp);
      float4 r1 = *(const float4*)(rp + 4);
      float4 r2 = *(const float4*)(rp + 8);
      float v[10] = {r0.x, r0.y, r0.z, r0.w, r1.x, r1.y, r1.z, r1.w, r2.x, r2.y};
      #pragma unroll
      for (int kx = 0; kx < 3; ++kx) {
        const float* wr = &wsm[ic][ky * 3 + kx][oc0];
        float4 w0 = *(const float4*)(wr);
        float4 w1 = *(const float4*)(wr + 4);
        float wv[8] = {w0.x, w0.y, w0.z, w0.w, w1.x, w1.y, w1.z, w1.w};
        #pragma unroll
        for (int o = 0; o < 8; ++o)
          #pragma unroll
          for (int p = 0; p < 8; ++p)
            acc[o][p] += wv[o] * v[p + kx];
      }
    }
  }
  #pragma unroll
  for (int o = 0; o < 8; ++o) {
    float bo = bias[oc0 + o];
    bf16 vals[8];
    #pragma unroll
    for (int p = 0; p < 8; ++p) vals[p] = __float2bfloat16(fmaxf(acc[o][p] + bo, 0.f));
    bf16* op = out + ((size_t)(b * 64 + oc0 + o) << 14) + (y0 + row) * 128 + xg;
    *(uint4*)op = *(const uint4*)vals;
  }
}

// ---------------- maxpool 2x2 -> channels-last padded xp[b][66][66][64] bf16 -------------
__global__ __launch_bounds__(256) void maxpool_cl(
    const bf16* __restrict__ y1, bf16* __restrict__ xp) {
  int wave = threadIdx.x >> 6;
  int lane = threadIdx.x & 63;
  int cell = blockIdx.x * 4 + wave;
  int b = blockIdx.y;
  int yp = cell / 66, xq = cell % 66;
  bf16* dst = xp + (((size_t)b * 66 + yp) * 66 + xq) * 64 + lane;
  if (yp == 0 || yp == 65 || xq == 0 || xq == 65) {
    *dst = __float2bfloat16(0.f);
    return;
  }
  int py = yp - 1, px = xq - 1;
  const bf16* sp = y1 + ((size_t)(b * 64 + lane) << 14) + (py * 2) * 128 + px * 2;
  float a = __bfloat162float(sp[0]), bq = __bfloat162float(sp[1]);
  float c = __bfloat162float(sp[128]), d = __bfloat162float(sp[129]);
  *dst = __float2bfloat16(fmaxf(fmaxf(a, bq), fmaxf(c, d)));
}

// ---------------- conv2 MFMA: xp (padded CL) -> f3[b][oc][4096] bf16, bias+ReLU ----------
__global__ __launch_bounds__(256) void conv2_mfma(
    const bf16* __restrict__ xp, const bf16* __restrict__ wcl,
    const float* __restrict__ bias, bf16* __restrict__ f3) {
  __shared__ unsigned short As[128 * 32];
  __shared__ unsigned short Bs[64 * 32];
  const int tid = threadIdx.x;
  const int b = blockIdx.y;
  const int y0 = blockIdx.x * 2;
  const int wave = tid >> 6;
  const int lane = tid & 63;
  const int wm = (wave & 1) << 6;
  const int wn = (wave >> 1) << 5;
  const char* xpB = (const char*)(xp + (size_t)b * 66 * 66 * 64);
  const char* wclB = (const char*)wcl;
  const int sr = tid >> 2;
  const int soff = (tid & 3) << 4;
  unsigned short* Al = As + wave * 512;
  unsigned short* Bl = Bs + wave * 512;
  f32x4 acc[4][2] = {};
  const int fr = lane & 15;
  const int fk = (lane >> 4) << 3;
  for (int tap = 0; tap < 9; ++tap) {
    int dy = tap / 3, dx = tap % 3;
    const char* arow0 = xpB + (((y0 + dy) * 66 + dx) << 7);
    const char* brow = wclB + (tap << 13);
    #pragma unroll
    for (int ch = 0; ch < 2; ++ch) {
      int coff = (ch << 6) + soff;
      async16(arow0 + sr * 128 + coff, Al);
      async16(arow0 + 66 * 128 + sr * 128 + coff, Al + 2048);
      async16(brow + sr * 128 + coff, Bl);
      __syncthreads();
      short8 af[4], bf[2];
      #pragma unroll
      for (int i = 0; i < 4; ++i)
        af[i] = *(const short8*)(As + ((wm + i * 16 + fr) << 5) + fk);
      #pragma unroll
      for (int i = 0; i < 2; ++i)
        bf[i] = *(const short8*)(Bs + ((wn + i * 16 + fr) << 5) + fk);
      #pragma unroll
      for (int mi = 0; mi < 4; ++mi)
        #pragma unroll
        for (int ni = 0; ni < 2; ++ni)
          acc[mi][ni] = __builtin_amdgcn_mfma_f32_16x16x32_bf16(af[mi], bf[ni], acc[mi][ni], 0, 0, 0);
      __syncthreads();
    }
  }
  const int cr = (lane >> 4) << 2;
  const int cc = lane & 15;
  #pragma unroll
  for (int ni = 0; ni < 2; ++ni) {
    int oc = wn + ni * 16 + cc;
    float bv = bias[oc];
    #pragma unroll
    for (int mi = 0; mi < 4; ++mi) {
      int pxb = wm + mi * 16 + cr;
      int y = y0 + (pxb >> 6), xb = pxb & 63;
      bf16 vals[4];
      #pragma unroll
      for (int r = 0; r < 4; ++r)
        vals[r] = __float2bfloat16(fmaxf(acc[mi][ni][r] + bv, 0.f));
      bf16* op = f3 + (((size_t)(b * 64 + oc)) << 12) + y * 64 + xb;
      *(us4*)op = *(const us4*)vals;
    }
  }
}

// ---------------- fused attention: one block per (b,h), S=64, dh=192, bf16 MFMA ----------
__global__ __launch_bounds__(256) void attn_fused(
    const bf16* __restrict__ qkv, bf16* __restrict__ o, float scale) {
  __shared__ unsigned short Qs[64][216];
  __shared__ unsigned short Ks[64][216];
  __shared__ unsigned short Vt[192][72];
  __shared__ unsigned short Ps[64][72];
  const int tid = threadIdx.x;
  const int b = blockIdx.x >> 2, h = blockIdx.x & 3;
  const unsigned short* base = (const unsigned short*)qkv + (size_t)b * 64 * 2304 + h * 192;
  for (int c = tid; c < 1536; c += 256) {
    int tok = c / 24, idx = (c % 24) * 8;
    const unsigned short* rp = base + (size_t)tok * 2304 + idx;
    short8 qv = *(const short8*)(rp);
    short8 kv = *(const short8*)(rp + 768);
    short8 vv = *(const short8*)(rp + 1536);
    *(short8*)&Qs[tok][idx] = qv;
    *(short8*)&Ks[tok][idx] = kv;
    #pragma unroll
    for (int j = 0; j < 8; ++j) Vt[idx + j][tok] = (unsigned short)vv[j];
  }
  __syncthreads();
  const int wave = tid >> 6, lane = tid & 63;
  const int fr = lane & 15;
  const int fk = (lane >> 4) << 3;
  f32x4 accs[4] = {};
  #pragma unroll
  for (int kk = 0; kk < 6; ++kk) {
    short8 aq = *(const short8*)&Qs[wave * 16 + fr][kk * 32 + fk];
    #pragma unroll
    for (int n = 0; n < 4; ++n) {
      short8 bk = *(const short8*)&Ks[n * 16 + fr][kk * 32 + fk];
      accs[n] = __builtin_amdgcn_mfma_f32_16x16x32_bf16(aq, bk, accs[n], 0, 0, 0);
    }
  }
  const int cr = (lane >> 4) << 2;
  const int cc = lane & 15;
  #pragma unroll
  for (int r = 0; r < 4; ++r) {
    float v0 = accs[0][r] * scale, v1 = accs[1][r] * scale;
    float v2 = accs[2][r] * scale, v3 = accs[3][r] * scale;
    float m = fmaxf(fmaxf(v0, v1), fmaxf(v2, v3));
    #pragma unroll
    for (int off = 8; off; off >>= 1) m = fmaxf(m, __shfl_xor(m, off));
    float e0 = __expf(v0 - m), e1 = __expf(v1 - m);
    float e2 = __expf(v2 - m), e3 = __expf(v3 - m);
    float s = e0 + e1 + e2 + e3;
    #pragma unroll
    for (int off = 8; off; off >>= 1) s += __shfl_xor(s, off);
    float inv = 1.f / s;
    int q = wave * 16 + cr + r;
    Ps[q][0 * 16 + cc] = __bfloat16_as_ushort(__float2bfloat16(e0 * inv));
    Ps[q][1 * 16 + cc] = __bfloat16_as_ushort(__float2bfloat16(e1 * inv));
    Ps[q][2 * 16 + cc] = __bfloat16_as_ushort(__float2bfloat16(e2 * inv));
    Ps[q][3 * 16 + cc] = __bfloat16_as_ushort(__float2bfloat16(e3 * inv));
  }
  __syncthreads();
  f32x4 acco[12] = {};
  #pragma unroll
  for (int kk = 0; kk < 2; ++kk) {
    short8 ap = *(const short8*)&Ps[wave * 16 + fr][kk * 32 + fk];
    #pragma unroll
    for (int j = 0; j < 12; ++j) {
      short8 bv = *(const short8*)&Vt[j * 16 + fr][kk * 32 + fk];
      acco[j] = __builtin_amdgcn_mfma_f32_16x16x32_bf16(ap, bv, acco[j], 0, 0, 0);
    }
  }
  bf16* ob = o + (size_t)(b * 64) * 768 + h * 192;
  #pragma unroll
  for (int j = 0; j < 12; ++j) {
    int d = j * 16 + cc;
    #pragma unroll
    for (int r = 0; r < 4; ++r) {
      int q = wave * 16 + cr + r;
      ob[(size_t)q * 768 + d] = __float2bfloat16(acco[j][r]);
    }
  }
}

// ---------------- fc2 + transform params fused: one block per m ----------------
__global__ __launch_bounds__(256) void fc2_params(
    const bf16* __restrict__ A, const float* __restrict__ Bw,
    const float* __restrict__ bias, float* __restrict__ par,
    float* __restrict__ trans_out, int K) {
  __shared__ float sm[4];
  int m = blockIdx.x;
  int n = threadIdx.x >> 6;
  int lane = threadIdx.x & 63;
  const bf16* a = A + (size_t)m * K;
  const float* bb = Bw + (size_t)n * K;
  float acc = 0.f;
  for (int k = lane; k < K; k += 64)
    acc += __bfloat162float(a[k]) * bb[k];
  for (int off = 32; off; off >>= 1) acc += __shfl_xor(acc, off);
  if (lane == 0) sm[n] = acc + bias[n];
  __syncthreads();
  if (threadIdx.x == 0) {
    float t0 = sm[0], t1 = sm[1], t2 = sm[2], t3 = sm[3];
    float trx = tanhf(t0), tryy = tanhf(t1);
    float s = (1.f / (1.f + expf(-t2))) * 0.3f;
    float rot = tanhf(t3) * PI_F;
    float c = cosf(rot), sn = sinf(rot);
    float x_ext = fminf(s * fabsf(c) + s * fabsf(sn), 1.f);
    float y_ext = fminf(s * fabsf(sn) + s * fabsf(c), 1.f);
    float tx = trx * (1.f - x_ext);
    float ty = tryy * (1.f - y_ext);
    par[m * 8 + 0] = s * c;
    par[m * 8 + 1] = -s * sn;
    par[m * 8 + 2] = s * sn;
    par[m * 8 + 3] = s * c;
    par[m * 8 + 4] = tx;
    par[m * 8 + 5] = ty;
    trans_out[m * 2 + 0] = tx;
    trans_out[m * 2 + 1] = ty;
  }
}

// ---------------- bilinear grid sample (fp32 x) ----------------
__global__ __launch_bounds__(256) void sample_k(
    const float* __restrict__ x, const float* __restrict__ par, float* __restrict__ out) {
  int tid = blockIdx.x * 256 + threadIdx.x;
  if (tid >= 32 * 64 * 3 * 256) return;
  int pj = tid & 15, pi = (tid >> 4) & 15;
  int c = (tid >> 8) % 3;
  int bp = tid / 768;
  int b = bp >> 6;
  const float* pp = par + bp * 8;
  float ta = pp[0], tb = pp[1], tc = pp[2], td = pp[3], tx = pp[4], ty = pp[5];
  float bj = (2.f * pj + 1.f) / 16.f - 1.f;
  float bi = (2.f * pi + 1.f) / 16.f - 1.f;
  float gx = ta * bj + tb * bi + tx;
  float gy = tc * bj + td * bi + ty;
  float xs = ((gx + 1.f) * 128.f - 1.f) * 0.5f;
  float ys = ((gy + 1.f) * 128.f - 1.f) * 0.5f;
  float x0f = floorf(xs), y0f = floorf(ys);
  float wx = xs - x0f, wy = ys - y0f;
  int x0 = (int)x0f, y0 = (int)y0f, x1 = x0 + 1, y1 = y0 + 1;
  const float* img = x + ((size_t)b * 3 + c) * 16384;
  auto g = [&](int yi, int xi) -> float {
    bool v = (xi >= 0) && (xi < 128) && (yi >= 0) && (yi < 128);
    int yc = yi < 0 ? 0 : (yi > 127 ? 127 : yi);
    int xc = xi < 0 ? 0 : (xi > 127 ? 127 : xi);
    float val = img[yc * 128 + xc];
    return v ? val : 0.f;
  };
  float v00 = g(y0, x0), v01 = g(y0, x1), v10 = g(y1, x0), v11 = g(y1, x1);
  out[tid] = v00 * (1.f - wx) * (1.f - wy) + v01 * wx * (1.f - wy) +
             v10 * (1.f - wx) * wy + v11 * wx * wy;
}

extern "C" void kernel_launch(void* const* d_in, const int* in_sizes, int n_in,
                              void* d_out, int out_size, void* d_ws, size_t ws_size,
                              hipStream_t stream) {
  const float* x        = (const float*)d_in[0];
  const float* conv1_w  = (const float*)d_in[1];
  const float* conv1_b  = (const float*)d_in[2];
  const float* a1_in_w  = (const float*)d_in[3];
  const float* a1_in_b  = (const float*)d_in[4];
  const float* a1_qkv_w = (const float*)d_in[5];
  const float* a1_qkv_b = (const float*)d_in[6];
  const float* a1_out_w = (const float*)d_in[7];
  const float* a1_out_b = (const float*)d_in[8];
  const float* a1_proj_w = (const float*)d_in[9];
  const float* a1_proj_b = (const float*)d_in[10];
  const float* conv2_w  = (const float*)d_in[11];
  const float* conv2_b  = (const float*)d_in[12];
  const float* a2_in_w  = (const float*)d_in[13];
  const float* a2_in_b  = (const float*)d_in[14];
  const float* a2_qkv_w = (const float*)d_in[15];
  const float* a2_qkv_b = (const float*)d_in[16];
  const float* a2_out_w = (const float*)d_in[17];
  const float* a2_out_b = (const float*)d_in[18];
  const float* a2_proj_w = (const float*)d_in[19];
  const float* a2_proj_b = (const float*)d_in[20];
  const float* fc1_w    = (const float*)d_in[21];
  const float* fc1_b    = (const float*)d_in[22];
  const float* fc2_w    = (const float*)d_in[23];
  const float* fc2_b    = (const float*)d_in[24];
  float* out = (float*)d_out;

  char* ws = (char*)d_ws;
  bf16*  f1   = (bf16*)(ws + 0);            // conv1 out / proj1 out (y1) / f3+h1 later
  bf16*  y1   = f1;
  bf16*  f3   = (bf16*)(ws + 0);
  bf16*  h1   = (bf16*)(ws + 33554432);
  float* part = (float*)(ws + 83886080);    // split-K partials (50 MB)
  bf16*  xp   = (bf16*)(ws + 83886080);     // padded CL pool out (aliases part)
  bf16*  t    = (bf16*)(ws + 134217728);
  bf16*  qkv  = (bf16*)(ws + 137363456);
  bf16*  o    = (bf16*)(ws + 158334976);
  bf16*  ao   = (bf16*)(ws + 161480704);
  bf16*  y2   = (bf16*)(ws + 164626432);
  float* par  = (float*)(ws + 181436416);
  bf16*  wcl  = (bf16*)(ws + 181501952);    // conv2 weights [tap][oc][ic], 74 KB

  const float scale = 0.07216878364870323f; // 1/sqrt(192)

  conv3x3_relu_c3_fast<<<dim3(64, 32), 256, 0, stream>>>(x, conv1_w, conv1_b, f1);
  // t1 = f1 @ a1_in_w^T, split-K 8 (z XCD-affine)
  gemm_bf16<0, 8><<<96 * 8, 256, 0, stream>>>((const unsigned short*)f1, a1_in_w, nullptr, part, 2048, 768, 16384, 2048);
  reduce_bias_k<<<1536, 256, 0, stream>>>(part, a1_in_b, t, 2048 * 768, 768, 8, 0);
  gemm_bf16<2, 1><<<288, 256, 0, stream>>>((const unsigned short*)t, a1_qkv_w, a1_qkv_b, qkv, 2048, 2304, 768, 768);
  attn_fused<<<128, 256, 0, stream>>>(qkv, o, scale);
  gemm_bf16<0, 3><<<96 * 3, 256, 0, stream>>>((const unsigned short*)o, a1_out_w, nullptr, part, 2048, 768, 768, 256);
  reduce_bias_k<<<1536, 256, 0, stream>>>(part, a1_out_b, ao, 2048 * 768, 768, 3, 0);
  gemm_bf16<2, 1><<<2048, 256, 0, stream>>>((const unsigned short*)ao, a1_proj_w, a1_proj_b, y1, 2048, 16384, 768, 768);
  cvt_wcl_k<<<144, 256, 0, stream>>>(conv2_w, wcl);
  maxpool_cl<<<dim3(1089, 32), 256, 0, stream>>>(y1, xp);
  conv2_mfma<<<dim3(32, 32), 256, 0, stream>>>(xp, wcl, conv2_b, f3);
  gemm_bf16<0, 4><<<96 * 4, 256, 0, stream>>>((const unsigned short*)f3, a2_in_w, nullptr, part, 2048, 768, 4096, 1024);
  reduce_bias_k<<<1536, 256, 0, stream>>>(part, a2_in_b, t, 2048 * 768, 768, 4, 0);
  gemm_bf16<2, 1><<<288, 256, 0, stream>>>((const unsigned short*)t, a2_qkv_w, a2_qkv_b, qkv, 2048, 2304, 768, 768);
  attn_fused<<<128, 256, 0, stream>>>(qkv, o, scale);
  gemm_bf16<0, 3><<<96 * 3, 256, 0, stream>>>((const unsigned short*)o, a2_out_w, nullptr, part, 2048, 768, 768, 256);
  reduce_bias_k<<<1536, 256, 0, stream>>>(part, a2_out_b, ao, 2048 * 768, 768, 3, 0);
  gemm_bf16<2, 1><<<512, 256, 0, stream>>>((const unsigned short*)ao, a2_proj_w, a2_proj_b, y2, 2048, 4096, 768, 768);
  gemm_bf16<0, 2><<<256 * 2, 256, 0, stream>>>((const unsigned short*)y2, fc1_w, nullptr, part, 2048, 2048, 4096, 2048);
  reduce_bias_k<<<4096, 256, 0, stream>>>(part, fc1_b, h1, 2048 * 2048, 2048, 2, 1);
  fc2_params<<<2048, 256, 0, stream>>>(h1, fc2_w, fc2_b, par, out + 1572864, 2048);
  sample_k<<<6144, 256, 0, stream>>>(x, par, out);
}